// Round 3
// baseline (571.580 us; speedup 1.0000x reference)
//
#include <hip/hip_runtime.h>
#include <hip/hip_bf16.h>

#define N_SRCN 50000
#define N_DSTN 50000
#define EDGES  800000
#define HEADS  8
#define NEG    0.2f

typedef __attribute__((ext_vector_type(8))) short short8v;   // 8 x bf16 bits
typedef __attribute__((ext_vector_type(4))) float floatx4;   // MFMA acc

static __device__ __forceinline__ short f2bf(float f) {
  __hip_bfloat16 h = __float2bfloat16(f);
  short s;
  __builtin_memcpy(&s, &h, 2);
  return s;
}

// ---- pack W[256,256] (row-major, KxN) into fragment-major bf16 array -------
// Bf[((kk*16 + nb)*64 + l)*8 + j] = bf16(W[kk*32 + (l>>4)*8 + j][nb*16 + (l&15)])
// kk: MFMA-K step (K=256 -> 8 steps of 32), nb: n-fragment (N=256 -> 16), l: lane.
__global__ void bfrag_k(const float* __restrict__ W, short* __restrict__ Bf) {
  int t = blockIdx.x * 256 + threadIdx.x;  // [0, 8*16*64)
  if (t >= 8 * 16 * 64) return;
  int l = t & 63;
  int nb = (t >> 6) & 15;
  int kk = t >> 10;
  int n = nb * 16 + (l & 15);
  int kbase = kk * 32 + ((l >> 4) * 8);
  short* o = Bf + (size_t)t * 8;
#pragma unroll
  for (int j = 0; j < 8; ++j) o[j] = f2bf(W[(size_t)(kbase + j) * 256 + n]);
}

// ---- MFMA GEMM: C[50000,256] = A[50000,256] @ W, one wave per 16-row stripe -
__global__ __launch_bounds__(256) void gemm_mfma_k(const float* __restrict__ A,
                                                   const short* __restrict__ Bf,
                                                   float* __restrict__ C) {
  int rt = blockIdx.x * 4 + (threadIdx.x >> 6);  // row-tile id, 16 rows each
  if (rt >= 3125) return;                        // 50000 = 3125*16 exactly
  const int l = threadIdx.x & 63;
  const int r0 = rt * 16;
  const int arow = r0 + (l & 15);
  const int kch = (l >> 4) * 8;

  floatx4 acc[16];
#pragma unroll
  for (int i = 0; i < 16; ++i) acc[i] = (floatx4){0.f, 0.f, 0.f, 0.f};

  for (int kk = 0; kk < 8; ++kk) {
    const float* ap = A + (size_t)arow * 256 + kk * 32 + kch;
    float4 a0 = *(const float4*)ap;
    float4 a1 = *(const float4*)(ap + 4);
    short8v af;
    af[0] = f2bf(a0.x); af[1] = f2bf(a0.y); af[2] = f2bf(a0.z); af[3] = f2bf(a0.w);
    af[4] = f2bf(a1.x); af[5] = f2bf(a1.y); af[6] = f2bf(a1.z); af[7] = f2bf(a1.w);
    const short* bbase = Bf + ((size_t)kk * 16 * 64) * 8 + (size_t)l * 8;
#pragma unroll
    for (int nf = 0; nf < 16; ++nf) {
      short8v bfv = *(const short8v*)(bbase + (size_t)nf * 64 * 8);
      acc[nf] = __builtin_amdgcn_mfma_f32_16x16x32_bf16(af, bfv, acc[nf], 0, 0, 0);
    }
  }
  // C/D layout: col = lane&15, row = (lane>>4)*4 + reg   [m89-verified]
  const int orow = r0 + (l >> 4) * 4;
  const int ocol = l & 15;
#pragma unroll
  for (int nf = 0; nf < 16; ++nf)
#pragma unroll
    for (int r = 0; r < 4; ++r)
      C[(size_t)(orow + r) * 256 + nf * 16 + ocol] = acc[nf][r];
}

// ---------------- rel = rel_emb @ rel_w : [512] ----------------
__global__ void rel_k(const float* __restrict__ rel_emb,
                      const float* __restrict__ rel_w,
                      float* __restrict__ rel) {
  int j = threadIdx.x;  // 512 threads
  float s = 0.f;
  for (int r = 0; r < 64; ++r) s += rel_emb[r] * rel_w[r * 512 + j];
  rel[j] = s;
}

// ------- per-node logits: elog[n,h] = sum_d f[n,h,d]*rel[h, off+d] ----------
__global__ void logits_k(const float* __restrict__ f,
                         const float* __restrict__ rel,
                         float* __restrict__ elog, int reloff, int N) {
  int i = blockIdx.x * blockDim.x + threadIdx.x;  // n*8 + h
  if (i >= N * HEADS) return;
  int n = i >> 3, h = i & 7;
  const float* fp = f + (size_t)n * 256 + h * 32;
  const float* rp = rel + h * 64 + reloff;
  float s = 0.f;
#pragma unroll
  for (int d = 0; d < 32; d += 4) {
    float4 a = *(const float4*)&fp[d];
    float4 b = *(const float4*)&rp[d];
    s += a.x * b.x + a.y * b.y + a.z * b.z + a.w * b.w;
  }
  elog[i] = s;
}

// ---------------- CSR build ----------------
__global__ void hist_k(const int* __restrict__ dst, int* __restrict__ counts) {
  int i = blockIdx.x * 256 + threadIdx.x;
  if (i < EDGES) atomicAdd(&counts[dst[i]], 1);
}

__global__ __launch_bounds__(1024) void scan_k(const int* __restrict__ counts,
                                               int* __restrict__ offs,
                                               int* __restrict__ cursor) {
  __shared__ int tmp[1024];
  __shared__ int running;
  if (threadIdx.x == 0) running = 0;
  __syncthreads();
  for (int base = 0; base < N_DSTN; base += 1024) {
    int i = base + (int)threadIdx.x;
    int v = (i < N_DSTN) ? counts[i] : 0;
    tmp[threadIdx.x] = v;
    __syncthreads();
    for (int off = 1; off < 1024; off <<= 1) {
      int t = (threadIdx.x >= (unsigned)off) ? tmp[threadIdx.x - off] : 0;
      __syncthreads();
      tmp[threadIdx.x] += t;
      __syncthreads();
    }
    int excl = tmp[threadIdx.x] - v + running;
    if (i < N_DSTN) {
      offs[i] = excl;
      cursor[i] = excl;
    }
    __syncthreads();
    if (threadIdx.x == 1023) running += tmp[1023];
    __syncthreads();
  }
  if (threadIdx.x == 0) offs[N_DSTN] = running;
}

__global__ void scatter_k(const int* __restrict__ src, const int* __restrict__ dst,
                          int* __restrict__ cursor, int* __restrict__ ssrc) {
  int i = blockIdx.x * 256 + threadIdx.x;
  if (i < EDGES) {
    int p = atomicAdd(&cursor[dst[i]], 1);
    ssrc[p] = src[i];
  }
}

// -------- per-dst-node softmax + aggregation: one wave per node -------------
__global__ __launch_bounds__(256) void aggr_k(const float* __restrict__ fs,
                                              const float* __restrict__ es,
                                              const float* __restrict__ ed,
                                              const int* __restrict__ offs,
                                              const int* __restrict__ ssrc,
                                              float* __restrict__ out) {
  int wid = (blockIdx.x * 256 + threadIdx.x) >> 6;  // node id
  int lane = threadIdx.x & 63;
  if (wid >= N_DSTN) return;
  const int beg = offs[wid], end = offs[wid + 1];
  const int h_a = lane & 7;   // head for passes A/B (lane = le*8 + h)
  const int le = lane >> 3;   // edge slot 0..7
  const int h_c = lane >> 3;  // head for pass C (lane = h*8 + dgrp)
  const float eda = ed[wid * 8 + h_a];
  const float edc = ed[wid * 8 + h_c];

  // Pass A: per-head max over edges
  float mx = -3.4e38f;
  for (int i = beg + le; i < end; i += 8) {
    float v = es[ssrc[i] * 8 + h_a] + eda;
    v = v > 0.f ? v : v * NEG;
    mx = fmaxf(mx, v);
  }
#pragma unroll
  for (int s = 8; s < 64; s <<= 1) mx = fmaxf(mx, __shfl_xor(mx, s));

  // Pass B: per-head sum of exp
  float sm = 0.f;
  for (int i = beg + le; i < end; i += 8) {
    float v = es[ssrc[i] * 8 + h_a] + eda;
    v = v > 0.f ? v : v * NEG;
    sm += __expf(v - mx);
  }
#pragma unroll
  for (int s = 8; s < 64; s <<= 1) sm += __shfl_xor(sm, s);

  // remap head-indexed stats to pass-C layout
  float m_c = __shfl(mx, h_c);
  float d_c = __shfl(sm, h_c);
  float inv = (end > beg) ? 1.f / d_c : 0.f;

  // Pass C: weighted gather-accumulate of fs rows
  const int col = lane * 4;  // h = col/32 = lane>>3, d = (lane&7)*4
  float4 acc = {0.f, 0.f, 0.f, 0.f};
  for (int i = beg; i < end; ++i) {
    int s = ssrc[i];
    float v = es[s * 8 + h_c] + edc;
    v = v > 0.f ? v : v * NEG;
    float a = __expf(v - m_c) * inv;
    float4 f = *(const float4*)&fs[(size_t)s * 256 + col];
    acc.x += f.x * a;
    acc.y += f.y * a;
    acc.z += f.z * a;
    acc.w += f.w * a;
  }
  float4 o = {fmaxf(acc.x, 0.f), fmaxf(acc.y, 0.f), fmaxf(acc.z, 0.f),
              fmaxf(acc.w, 0.f)};
  *(float4*)&out[(size_t)wid * 256 + col] = o;
}

extern "C" void kernel_launch(void* const* d_in, const int* in_sizes, int n_in,
                              void* d_out, int out_size, void* d_ws, size_t ws_size,
                              hipStream_t stream) {
  const float* feat_src = (const float*)d_in[0];
  const float* feat_dst = (const float*)d_in[1];
  const float* src_w = (const float*)d_in[2];
  const float* dst_w = (const float*)d_in[3];
  const float* rel_emb = (const float*)d_in[4];
  const float* rel_w = (const float*)d_in[5];
  const int* src_idx = (const int*)d_in[6];
  const int* dst_idx = (const int*)d_in[7];
  float* out = (float*)d_out;

  // workspace carve (~110 MB + 256 KB)
  float* fs = (float*)d_ws;                       // 50000*256
  float* fd = fs + (size_t)N_SRCN * 256;          // 50000*256
  float* rel = fd + (size_t)N_DSTN * 256;         // 512
  float* es = rel + 512;                          // 50000*8
  float* ed = es + (size_t)N_SRCN * 8;            // 50000*8
  int* counts = (int*)(ed + (size_t)N_DSTN * 8);  // 50000
  int* offs = counts + N_DSTN;                    // 50001
  int* cursor = offs + (N_DSTN + 1);              // 50000
  int* ssrc = cursor + N_DSTN;                    // 800000
  short* bfS = (short*)(ssrc + EDGES);            // 8*16*64*8 = 65536 shorts
  short* bfD = bfS + 65536;                       // 65536 shorts

  hipMemsetAsync(counts, 0, N_DSTN * sizeof(int), stream);

  bfrag_k<<<32, 256, 0, stream>>>(src_w, bfS);
  bfrag_k<<<32, 256, 0, stream>>>(dst_w, bfD);
  gemm_mfma_k<<<782, 256, 0, stream>>>(feat_src, bfS, fs);
  gemm_mfma_k<<<782, 256, 0, stream>>>(feat_dst, bfD, fd);
  rel_k<<<1, 512, 0, stream>>>(rel_emb, rel_w, rel);
  logits_k<<<(N_SRCN * HEADS + 255) / 256, 256, 0, stream>>>(fs, rel, es, 32, N_SRCN);
  logits_k<<<(N_DSTN * HEADS + 255) / 256, 256, 0, stream>>>(fd, rel, ed, 0, N_DSTN);
  hist_k<<<(EDGES + 255) / 256, 256, 0, stream>>>(dst_idx, counts);
  scan_k<<<1, 1024, 0, stream>>>(counts, offs, cursor);
  scatter_k<<<(EDGES + 255) / 256, 256, 0, stream>>>(src_idx, dst_idx, cursor, ssrc);
  aggr_k<<<(N_DSTN + 3) / 4, 256, 0, stream>>>(fs, es, ed, offs, ssrc, out);
}

// Round 4
// 423.653 us; speedup vs baseline: 1.3492x; 1.3492x over previous
//
#include <hip/hip_runtime.h>
#include <hip/hip_bf16.h>

#define N_SRCN 50000
#define N_DSTN 50000
#define EDGES  800000
#define HEADS  8
#define NEG    0.2f

typedef __attribute__((ext_vector_type(8))) short short8v;   // 8 x bf16 bits
typedef __attribute__((ext_vector_type(4))) float floatx4;   // MFMA acc

static __device__ __forceinline__ unsigned short f2bf(float f) {
  __hip_bfloat16 h = __float2bfloat16(f);
  unsigned short s;
  __builtin_memcpy(&s, &h, 2);
  return s;
}
static __device__ __forceinline__ float bf2f(unsigned short u) {
  return __uint_as_float(((unsigned)u) << 16);
}

// ---- pack W[256,256] (row-major, KxN) into fragment-major bf16 array -------
// Bf[((kk*16 + nb)*64 + l)*8 + j] = bf16(W[kk*32 + (l>>4)*8 + j][nb*16 + (l&15)])
__global__ void bfrag_k(const float* __restrict__ W, short* __restrict__ Bf) {
  int t = blockIdx.x * 256 + threadIdx.x;  // [0, 8*16*64)
  if (t >= 8 * 16 * 64) return;
  int l = t & 63;
  int nb = (t >> 6) & 15;
  int kk = t >> 10;
  int n = nb * 16 + (l & 15);
  int kbase = kk * 32 + ((l >> 4) * 8);
  short* o = Bf + (size_t)t * 8;
#pragma unroll
  for (int j = 0; j < 8; ++j) o[j] = (short)f2bf(W[(size_t)(kbase + j) * 256 + n]);
}

// ---- fused MFMA GEMM + logits epilogue -------------------------------------
// C = A[50000,256] @ W  (one wave per 16-row stripe).
// Writes elog[n,h] = sum_d C[n, h*32+d] * rel[h*64 + reloff + d].
// If fs16 != nullptr, also writes C as bf16 (for the aggregation gather).
// fd (fp32 projection) is never materialized.
__global__ __launch_bounds__(256) void gemm_fused_k(const float* __restrict__ A,
                                                    const short* __restrict__ Bf,
                                                    const float* __restrict__ rel,
                                                    float* __restrict__ elog,
                                                    unsigned short* __restrict__ fs16,
                                                    int reloff) {
  int rt = blockIdx.x * 4 + (threadIdx.x >> 6);  // row-tile id, 16 rows each
  if (rt >= 3125) return;                        // 50000 = 3125*16 exactly
  const int l = threadIdx.x & 63;
  const int r0 = rt * 16;
  const int arow = r0 + (l & 15);
  const int kch = (l >> 4) * 8;

  floatx4 acc[16];
#pragma unroll
  for (int i = 0; i < 16; ++i) acc[i] = (floatx4){0.f, 0.f, 0.f, 0.f};

  for (int kk = 0; kk < 8; ++kk) {
    const float* ap = A + (size_t)arow * 256 + kk * 32 + kch;
    float4 a0 = *(const float4*)ap;
    float4 a1 = *(const float4*)(ap + 4);
    short8v af;
    af[0] = f2bf(a0.x); af[1] = f2bf(a0.y); af[2] = f2bf(a0.z); af[3] = f2bf(a0.w);
    af[4] = f2bf(a1.x); af[5] = f2bf(a1.y); af[6] = f2bf(a1.z); af[7] = f2bf(a1.w);
    const short* bbase = Bf + ((size_t)kk * 16 * 64) * 8 + (size_t)l * 8;
#pragma unroll
    for (int nf = 0; nf < 16; ++nf) {
      short8v bfv = *(const short8v*)(bbase + (size_t)nf * 64 * 8);
      acc[nf] = __builtin_amdgcn_mfma_f32_16x16x32_bf16(af, bfv, acc[nf], 0, 0, 0);
    }
  }
  // C/D layout: col = lane&15, row = (lane>>4)*4 + reg   [m89-verified]
  const int orow = r0 + (l >> 4) * 4;
  const int ocol = l & 15;

  // optional bf16 feature write
  if (fs16) {
#pragma unroll
    for (int nf = 0; nf < 16; ++nf)
#pragma unroll
      for (int r = 0; r < 4; ++r)
        fs16[(size_t)(orow + r) * 256 + nf * 16 + ocol] = f2bf(acc[nf][r]);
  }

  // fused logits: head h covers col groups nf=2h (d=ocol) and nf=2h+1 (d=16+ocol)
  float relv[16];
#pragma unroll
  for (int nf = 0; nf < 16; ++nf)
    relv[nf] = rel[(nf >> 1) * 64 + reloff + (nf & 1) * 16 + ocol];

  float part[8][4];
#pragma unroll
  for (int h = 0; h < 8; ++h)
#pragma unroll
    for (int r = 0; r < 4; ++r)
      part[h][r] = acc[2 * h][r] * relv[2 * h] + acc[2 * h + 1][r] * relv[2 * h + 1];
#pragma unroll
  for (int m = 1; m < 16; m <<= 1)
#pragma unroll
    for (int h = 0; h < 8; ++h)
#pragma unroll
      for (int r = 0; r < 4; ++r)
        part[h][r] += __shfl_xor(part[h][r], m);
  // every lane in a 16-lane row-group now holds all 8 head sums; lane ocol==h writes
#pragma unroll
  for (int h = 0; h < 8; ++h) {
    if (ocol == h) {
#pragma unroll
      for (int r = 0; r < 4; ++r)
        elog[(size_t)(orow + r) * 8 + h] = part[h][r];
    }
  }
}

// ---------------- rel = rel_emb @ rel_w : [512] ----------------
__global__ void rel_k(const float* __restrict__ rel_emb,
                      const float* __restrict__ rel_w,
                      float* __restrict__ rel) {
  int j = threadIdx.x;  // 512 threads
  float s = 0.f;
  for (int r = 0; r < 64; ++r) s += rel_emb[r] * rel_w[r * 512 + j];
  rel[j] = s;
}

// ---------------- CSR build ----------------
__global__ void hist_k(const int* __restrict__ dst, int* __restrict__ counts) {
  int i = blockIdx.x * 256 + threadIdx.x;
  if (i < EDGES) atomicAdd(&counts[dst[i]], 1);
}

// hierarchical exclusive scan of counts[50000] -> offs, cursor
__global__ __launch_bounds__(256) void scan1_k(const int* __restrict__ counts,
                                               int* __restrict__ offs,
                                               int* __restrict__ bsum) {
  int i = blockIdx.x * 256 + (int)threadIdx.x;
  int lane = threadIdx.x & 63, w = threadIdx.x >> 6;
  int v = (i < N_DSTN) ? counts[i] : 0;
  int inc = v;
#pragma unroll
  for (int off = 1; off < 64; off <<= 1) {
    int n = __shfl_up(inc, off);
    if (lane >= off) inc += n;
  }
  __shared__ int wt[4];
  if (lane == 63) wt[w] = inc;
  __syncthreads();
  int base = (w > 0 ? wt[0] : 0) + (w > 1 ? wt[1] : 0) + (w > 2 ? wt[2] : 0);
  if (i < N_DSTN) offs[i] = base + inc - v;  // block-local exclusive
  if (threadIdx.x == 255) bsum[blockIdx.x] = base + inc;
}

__global__ __launch_bounds__(256) void scan2_k(int* __restrict__ bsum,
                                               int* __restrict__ bbase) {
  int t = threadIdx.x;
  int lane = t & 63, w = t >> 6;
  int v = (t < 196) ? bsum[t] : 0;
  int inc = v;
#pragma unroll
  for (int off = 1; off < 64; off <<= 1) {
    int n = __shfl_up(inc, off);
    if (lane >= off) inc += n;
  }
  __shared__ int wt[4];
  if (lane == 63) wt[w] = inc;
  __syncthreads();
  int base = (w > 0 ? wt[0] : 0) + (w > 1 ? wt[1] : 0) + (w > 2 ? wt[2] : 0);
  if (t < 196) bbase[t] = base + inc - v;
}

__global__ __launch_bounds__(256) void scan3_k(int* __restrict__ offs,
                                               const int* __restrict__ bbase,
                                               int* __restrict__ cursor) {
  int i = blockIdx.x * 256 + (int)threadIdx.x;
  if (i < N_DSTN) {
    int o = offs[i] + bbase[blockIdx.x];
    offs[i] = o;
    cursor[i] = o;
  }
  if (i == 0) offs[N_DSTN] = EDGES;  // all edges have in-range dst
}

__global__ void scatter_k(const int* __restrict__ src, const int* __restrict__ dst,
                          int* __restrict__ cursor, int* __restrict__ ssrc) {
  int i = blockIdx.x * 256 + threadIdx.x;
  if (i < EDGES) {
    int p = atomicAdd(&cursor[dst[i]], 1);
    ssrc[p] = src[i];
  }
}

// -------- per-dst-node softmax + aggregation: one wave per node -------------
__global__ __launch_bounds__(256) void aggr_k(const unsigned short* __restrict__ fs16,
                                              const float* __restrict__ es,
                                              const float* __restrict__ ed,
                                              const int* __restrict__ offs,
                                              const int* __restrict__ ssrc,
                                              float* __restrict__ out) {
  int wid = (blockIdx.x * 256 + threadIdx.x) >> 6;  // node id
  int lane = threadIdx.x & 63;
  if (wid >= N_DSTN) return;
  const int beg = offs[wid], end = offs[wid + 1];
  const int h_a = lane & 7;   // head for passes A/B (lane = le*8 + h)
  const int le = lane >> 3;   // edge slot 0..7
  const int h_c = lane >> 3;  // head for pass C (lane = h*8 + dgrp)
  const float eda = ed[wid * 8 + h_a];
  const float edc = ed[wid * 8 + h_c];

  // Pass A: per-head max over edges
  float mx = -3.4e38f;
  for (int i = beg + le; i < end; i += 8) {
    float v = es[ssrc[i] * 8 + h_a] + eda;
    v = v > 0.f ? v : v * NEG;
    mx = fmaxf(mx, v);
  }
#pragma unroll
  for (int s = 8; s < 64; s <<= 1) mx = fmaxf(mx, __shfl_xor(mx, s));

  // Pass B: per-head sum of exp
  float sm = 0.f;
  for (int i = beg + le; i < end; i += 8) {
    float v = es[ssrc[i] * 8 + h_a] + eda;
    v = v > 0.f ? v : v * NEG;
    sm += __expf(v - mx);
  }
#pragma unroll
  for (int s = 8; s < 64; s <<= 1) sm += __shfl_xor(sm, s);

  // remap head-indexed stats to pass-C layout
  float m_c = __shfl(mx, h_c);
  float d_c = __shfl(sm, h_c);
  float inv = (end > beg) ? 1.f / d_c : 0.f;

  // Pass C: weighted gather-accumulate of bf16 fs rows
  const int col = lane * 4;  // h = (lane*4)/32 = lane>>3, d = (lane&7)*4
  float4 acc = {0.f, 0.f, 0.f, 0.f};
  for (int i = beg; i < end; ++i) {
    int s = ssrc[i];
    float v = es[s * 8 + h_c] + edc;
    v = v > 0.f ? v : v * NEG;
    float a = __expf(v - m_c) * inv;
    ushort4 fv = *(const ushort4*)&fs16[(size_t)s * 256 + col];
    acc.x += bf2f(fv.x) * a;
    acc.y += bf2f(fv.y) * a;
    acc.z += bf2f(fv.z) * a;
    acc.w += bf2f(fv.w) * a;
  }
  float4 o = {fmaxf(acc.x, 0.f), fmaxf(acc.y, 0.f), fmaxf(acc.z, 0.f),
              fmaxf(acc.w, 0.f)};
  *(float4*)&out[(size_t)wid * 256 + col] = o;
}

extern "C" void kernel_launch(void* const* d_in, const int* in_sizes, int n_in,
                              void* d_out, int out_size, void* d_ws, size_t ws_size,
                              hipStream_t stream) {
  const float* feat_src = (const float*)d_in[0];
  const float* feat_dst = (const float*)d_in[1];
  const float* src_w = (const float*)d_in[2];
  const float* dst_w = (const float*)d_in[3];
  const float* rel_emb = (const float*)d_in[4];
  const float* rel_w = (const float*)d_in[5];
  const int* src_idx = (const int*)d_in[6];
  const int* dst_idx = (const int*)d_in[7];
  float* out = (float*)d_out;

  // workspace carve (~34 MB)
  unsigned short* fs16 = (unsigned short*)d_ws;     // 50000*256 bf16
  float* rel = (float*)(fs16 + (size_t)N_SRCN * 256);  // 512
  float* es = rel + 512;                            // 50000*8
  float* ed = es + (size_t)N_SRCN * 8;              // 50000*8
  int* counts = (int*)(ed + (size_t)N_DSTN * 8);    // 50000
  int* offs = counts + N_DSTN;                      // 50001
  int* cursor = offs + (N_DSTN + 1);                // 50000
  int* bsum = cursor + N_DSTN;                      // 196
  int* bbase = bsum + 256;                          // 196
  int* ssrc = bbase + 256;                          // 800000
  short* bfS = (short*)(ssrc + EDGES);              // 65536 shorts
  short* bfD = bfS + 65536;                         // 65536 shorts

  hipMemsetAsync(counts, 0, N_DSTN * sizeof(int), stream);

  rel_k<<<1, 512, 0, stream>>>(rel_emb, rel_w, rel);
  bfrag_k<<<32, 256, 0, stream>>>(src_w, bfS);
  bfrag_k<<<32, 256, 0, stream>>>(dst_w, bfD);
  // src: project + es logits + bf16 features; dst: logits only (no fd!)
  gemm_fused_k<<<782, 256, 0, stream>>>(feat_src, bfS, rel, es, fs16, 32);
  gemm_fused_k<<<782, 256, 0, stream>>>(feat_dst, bfD, rel, ed, nullptr, 0);
  hist_k<<<(EDGES + 255) / 256, 256, 0, stream>>>(dst_idx, counts);
  scan1_k<<<196, 256, 0, stream>>>(counts, offs, bsum);
  scan2_k<<<1, 256, 0, stream>>>(bsum, bbase);
  scan3_k<<<196, 256, 0, stream>>>(offs, bbase, cursor);
  scatter_k<<<(EDGES + 255) / 256, 256, 0, stream>>>(src_idx, dst_idx, cursor, ssrc);
  aggr_k<<<(N_DSTN + 3) / 4, 256, 0, stream>>>(fs16, es, ed, offs, ssrc, out);
}

// Round 10
// 361.434 us; speedup vs baseline: 1.5814x; 1.1721x over previous
//
#include <hip/hip_runtime.h>
#include <hip/hip_bf16.h>

#define N_SRCN 50000
#define N_DSTN 50000
#define EDGES  800000
#define HEADS  8
#define NEG    0.2f

typedef __attribute__((ext_vector_type(8))) short short8v;   // 8 x bf16 bits
typedef __attribute__((ext_vector_type(4))) float floatx4;   // MFMA acc

static __device__ __forceinline__ unsigned short f2bf(float f) {
  __hip_bfloat16 h = __float2bfloat16(f);
  unsigned short s;
  __builtin_memcpy(&s, &h, 2);
  return s;
}
static __device__ __forceinline__ float bf2f(unsigned short u) {
  return __uint_as_float(((unsigned)u) << 16);
}

// ---- pack W[256,256] (row-major, KxN) into fragment-major bf16 array -------
// Bf[((kk*16 + nb)*64 + l)*8 + j] = bf16(W[kk*32 + (l>>4)*8 + j][nb*16 + (l&15)])
__global__ void bfrag_k(const float* __restrict__ W, short* __restrict__ Bf) {
  int t = blockIdx.x * 256 + threadIdx.x;  // [0, 8*16*64)
  if (t >= 8 * 16 * 64) return;
  int l = t & 63;
  int nb = (t >> 6) & 15;
  int kk = t >> 10;
  int n = nb * 16 + (l & 15);
  int kbase = kk * 32 + ((l >> 4) * 8);
  short* o = Bf + (size_t)t * 8;
#pragma unroll
  for (int j = 0; j < 8; ++j) o[j] = (short)f2bf(W[(size_t)(kbase + j) * 256 + n]);
}

// ---- fused MFMA GEMM + logits epilogue, LDS-dbuf B staging -----------------
// One wave per 16-row stripe; 4 waves/block share Bf via LDS.
__global__ __launch_bounds__(256) void gemm_fused_k(const float* __restrict__ A,
                                                    const short* __restrict__ Bf,
                                                    const float* __restrict__ rel,
                                                    float* __restrict__ elog,
                                                    unsigned short* __restrict__ fs16,
                                                    int reloff) {
  __shared__ short bsm[2][8192];  // 2 x 16 KB (one kk-step of Bf)
  const int t = threadIdx.x;
  const int w = t >> 6, l = t & 63;
  int rt = blockIdx.x * 4 + w;
  if (rt > 3124) rt = 3124;  // clamp: duplicate last tile (identical writes, benign)
  const int r0 = rt * 16;
  const int arow = r0 + (l & 15);
  const int kch = (l >> 4) * 8;

  // stage Bf[kk] (16 KB) into bsm[buf]: 4 chunks x (4 waves x 1 KB), linear
#define STAGE(buf, kk)                                                          \
  {                                                                             \
    _Pragma("unroll")                                                           \
    for (int c = 0; c < 4; ++c) {                                               \
      const short* g = Bf + (size_t)(kk)*8192 + c * 2048 + w * 512 + l * 8;     \
      short* d = &bsm[buf][c * 2048 + w * 512]; /* wave-uniform base */         \
      __builtin_amdgcn_global_load_lds(                                         \
          (const __attribute__((address_space(1))) void*)g,                     \
          (__attribute__((address_space(3))) void*)d, 16, 0, 0);                \
    }                                                                           \
  }

  floatx4 acc[16];
#pragma unroll
  for (int i = 0; i < 16; ++i) acc[i] = (floatx4){0.f, 0.f, 0.f, 0.f};

  STAGE(0, 0);
  asm volatile("s_waitcnt vmcnt(0)" ::: "memory");
  __builtin_amdgcn_s_barrier();

  for (int kk = 0; kk < 8; ++kk) {
    const int cur = kk & 1;
    if (kk < 7) STAGE(cur ^ 1, kk + 1);
    const float* ap = A + (size_t)arow * 256 + kk * 32 + kch;
    float4 a0 = *(const float4*)ap;
    float4 a1 = *(const float4*)(ap + 4);
    short8v af;
    af[0] = f2bf(a0.x); af[1] = f2bf(a0.y); af[2] = f2bf(a0.z); af[3] = f2bf(a0.w);
    af[4] = f2bf(a1.x); af[5] = f2bf(a1.y); af[6] = f2bf(a1.z); af[7] = f2bf(a1.w);
#pragma unroll
    for (int nf = 0; nf < 16; ++nf) {
      short8v bfv = *(const short8v*)&bsm[cur][(nf * 64 + l) * 8];
      acc[nf] = __builtin_amdgcn_mfma_f32_16x16x32_bf16(af, bfv, acc[nf], 0, 0, 0);
    }
    if (kk < 7) {
      asm volatile("s_waitcnt vmcnt(0)" ::: "memory");
      __builtin_amdgcn_s_barrier();
    }
  }
#undef STAGE

  // C/D layout: col = lane&15, row = (lane>>4)*4 + reg   [m89-verified]
  const int orow = r0 + (l >> 4) * 4;
  const int ocol = l & 15;

  if (fs16) {
#pragma unroll
    for (int nf = 0; nf < 16; ++nf)
#pragma unroll
      for (int r = 0; r < 4; ++r)
        fs16[(size_t)(orow + r) * 256 + nf * 16 + ocol] = f2bf(acc[nf][r]);
  }

  // fused logits: head h covers col groups nf=2h (d=ocol) and nf=2h+1 (d=16+ocol)
  float relv[16];
#pragma unroll
  for (int nf = 0; nf < 16; ++nf)
    relv[nf] = rel[(nf >> 1) * 64 + reloff + (nf & 1) * 16 + ocol];

  float part[8][4];
#pragma unroll
  for (int h = 0; h < 8; ++h)
#pragma unroll
    for (int r = 0; r < 4; ++r)
      part[h][r] = acc[2 * h][r] * relv[2 * h] + acc[2 * h + 1][r] * relv[2 * h + 1];
#pragma unroll
  for (int m = 1; m < 16; m <<= 1)
#pragma unroll
    for (int h = 0; h < 8; ++h)
#pragma unroll
      for (int r = 0; r < 4; ++r)
        part[h][r] += __shfl_xor(part[h][r], m);
#pragma unroll
  for (int h = 0; h < 8; ++h) {
    if (ocol == h) {
#pragma unroll
      for (int r = 0; r < 4; ++r)
        elog[(size_t)(orow + r) * 8 + h] = part[h][r];
    }
  }
}

// ---------------- rel = rel_emb @ rel_w : [512] ----------------
__global__ void rel_k(const float* __restrict__ rel_emb,
                      const float* __restrict__ rel_w,
                      float* __restrict__ rel) {
  int j = threadIdx.x;  // 512 threads
  float s = 0.f;
  for (int r = 0; r < 64; ++r) s += rel_emb[r] * rel_w[r * 512 + j];
  rel[j] = s;
}

// ---------------- CSR build ----------------
__global__ void hist_k(const int* __restrict__ dst, int* __restrict__ counts) {
  int i = blockIdx.x * 256 + threadIdx.x;
  if (i < EDGES) atomicAdd(&counts[dst[i]], 1);
}

// hierarchical exclusive scan of counts[50000] -> offs, cursor
__global__ __launch_bounds__(256) void scan1_k(const int* __restrict__ counts,
                                               int* __restrict__ offs,
                                               int* __restrict__ bsum) {
  int i = blockIdx.x * 256 + (int)threadIdx.x;
  int lane = threadIdx.x & 63, w = threadIdx.x >> 6;
  int v = (i < N_DSTN) ? counts[i] : 0;
  int inc = v;
#pragma unroll
  for (int off = 1; off < 64; off <<= 1) {
    int n = __shfl_up(inc, off);
    if (lane >= off) inc += n;
  }
  __shared__ int wt[4];
  if (lane == 63) wt[w] = inc;
  __syncthreads();
  int base = (w > 0 ? wt[0] : 0) + (w > 1 ? wt[1] : 0) + (w > 2 ? wt[2] : 0);
  if (i < N_DSTN) offs[i] = base + inc - v;  // block-local exclusive
  if (threadIdx.x == 255) bsum[blockIdx.x] = base + inc;
}

__global__ __launch_bounds__(256) void scan2_k(int* __restrict__ bsum,
                                               int* __restrict__ bbase) {
  int t = threadIdx.x;
  int lane = t & 63, w = t >> 6;
  int v = (t < 196) ? bsum[t] : 0;
  int inc = v;
#pragma unroll
  for (int off = 1; off < 64; off <<= 1) {
    int n = __shfl_up(inc, off);
    if (lane >= off) inc += n;
  }
  __shared__ int wt[4];
  if (lane == 63) wt[w] = inc;
  __syncthreads();
  int base = (w > 0 ? wt[0] : 0) + (w > 1 ? wt[1] : 0) + (w > 2 ? wt[2] : 0);
  if (t < 196) bbase[t] = base + inc - v;
}

__global__ __launch_bounds__(256) void scan3_k(int* __restrict__ offs,
                                               const int* __restrict__ bbase,
                                               int* __restrict__ cursor) {
  int i = blockIdx.x * 256 + (int)threadIdx.x;
  if (i < N_DSTN) {
    int o = offs[i] + bbase[blockIdx.x];
    offs[i] = o;
    cursor[i] = o;
  }
  if (i == 0) offs[N_DSTN] = EDGES;  // all edges have in-range dst
}

__global__ void scatter_k(const int* __restrict__ src, const int* __restrict__ dst,
                          int* __restrict__ cursor, int* __restrict__ ssrc) {
  int i = blockIdx.x * 256 + threadIdx.x;
  if (i < EDGES) {
    int p = atomicAdd(&cursor[dst[i]], 1);
    ssrc[p] = src[i];
  }
}

// -------- per-dst-node softmax + aggregation: one wave per node -------------
__global__ __launch_bounds__(256) void aggr_k(const unsigned short* __restrict__ fs16,
                                              const float* __restrict__ es,
                                              const float* __restrict__ ed,
                                              const int* __restrict__ offs,
                                              const int* __restrict__ ssrc,
                                              float* __restrict__ out) {
  int wid = (blockIdx.x * 256 + threadIdx.x) >> 6;  // node id
  int lane = threadIdx.x & 63;
  if (wid >= N_DSTN) return;
  const int beg = offs[wid], end = offs[wid + 1];
  const int h_a = lane & 7;   // head for passes A/B (lane = le*8 + h)
  const int le = lane >> 3;   // edge slot 0..7
  const int h_c = lane >> 3;  // head for pass C (lane = h*8 + dgrp)
  const float eda = ed[wid * 8 + h_a];
  const float edc = ed[wid * 8 + h_c];

  // Pass A: per-head max over edges
  float mx = -3.4e38f;
  for (int i = beg + le; i < end; i += 8) {
    float v = es[ssrc[i] * 8 + h_a] + eda;
    v = v > 0.f ? v : v * NEG;
    mx = fmaxf(mx, v);
  }
#pragma unroll
  for (int s = 8; s < 64; s <<= 1) mx = fmaxf(mx, __shfl_xor(mx, s));

  // Pass B: per-head sum of exp
  float sm = 0.f;
  for (int i = beg + le; i < end; i += 8) {
    float v = es[ssrc[i] * 8 + h_a] + eda;
    v = v > 0.f ? v : v * NEG;
    sm += __expf(v - mx);
  }
#pragma unroll
  for (int s = 8; s < 64; s <<= 1) sm += __shfl_xor(sm, s);

  // remap head-indexed stats to pass-C layout
  float m_c = __shfl(mx, h_c);
  float d_c = __shfl(sm, h_c);
  float inv = (end > beg) ? 1.f / d_c : 0.f;

  // Pass C: weighted gather-accumulate of bf16 fs rows, 4x unrolled for MLP
  const int col = lane * 4;  // h = (lane*4)/32 = lane>>3, d = (lane&7)*4
  float4 acc = {0.f, 0.f, 0.f, 0.f};
  int i = beg;
  for (; i + 4 <= end; i += 4) {
    int s0 = ssrc[i], s1 = ssrc[i + 1], s2 = ssrc[i + 2], s3 = ssrc[i + 3];
    float e0 = es[s0 * 8 + h_c], e1 = es[s1 * 8 + h_c];
    float e2 = es[s2 * 8 + h_c], e3 = es[s3 * 8 + h_c];
    ushort4 f0 = *(const ushort4*)&fs16[(size_t)s0 * 256 + col];
    ushort4 f1 = *(const ushort4*)&fs16[(size_t)s1 * 256 + col];
    ushort4 f2 = *(const ushort4*)&fs16[(size_t)s2 * 256 + col];
    ushort4 f3 = *(const ushort4*)&fs16[(size_t)s3 * 256 + col];
    float v0 = e0 + edc; v0 = v0 > 0.f ? v0 : v0 * NEG;
    float v1 = e1 + edc; v1 = v1 > 0.f ? v1 : v1 * NEG;
    float v2 = e2 + edc; v2 = v2 > 0.f ? v2 : v2 * NEG;
    float v3 = e3 + edc; v3 = v3 > 0.f ? v3 : v3 * NEG;
    float a0 = __expf(v0 - m_c) * inv;
    float a1 = __expf(v1 - m_c) * inv;
    float a2 = __expf(v2 - m_c) * inv;
    float a3 = __expf(v3 - m_c) * inv;
    acc.x += bf2f(f0.x) * a0; acc.y += bf2f(f0.y) * a0;
    acc.z += bf2f(f0.z) * a0; acc.w += bf2f(f0.w) * a0;
    acc.x += bf2f(f1.x) * a1; acc.y += bf2f(f1.y) * a1;
    acc.z += bf2f(f1.z) * a1; acc.w += bf2f(f1.w) * a1;
    acc.x += bf2f(f2.x) * a2; acc.y += bf2f(f2.y) * a2;
    acc.z += bf2f(f2.z) * a2; acc.w += bf2f(f2.w) * a2;
    acc.x += bf2f(f3.x) * a3; acc.y += bf2f(f3.y) * a3;
    acc.z += bf2f(f3.z) * a3; acc.w += bf2f(f3.w) * a3;
  }
  for (; i < end; ++i) {
    int s = ssrc[i];
    float v = es[s * 8 + h_c] + edc;
    v = v > 0.f ? v : v * NEG;
    float a = __expf(v - m_c) * inv;
    ushort4 fv = *(const ushort4*)&fs16[(size_t)s * 256 + col];
    acc.x += bf2f(fv.x) * a;
    acc.y += bf2f(fv.y) * a;
    acc.z += bf2f(fv.z) * a;
    acc.w += bf2f(fv.w) * a;
  }
  float4 o = {fmaxf(acc.x, 0.f), fmaxf(acc.y, 0.f), fmaxf(acc.z, 0.f),
              fmaxf(acc.w, 0.f)};
  *(float4*)&out[(size_t)wid * 256 + col] = o;
}

extern "C" void kernel_launch(void* const* d_in, const int* in_sizes, int n_in,
                              void* d_out, int out_size, void* d_ws, size_t ws_size,
                              hipStream_t stream) {
  const float* feat_src = (const float*)d_in[0];
  const float* feat_dst = (const float*)d_in[1];
  const float* src_w = (const float*)d_in[2];
  const float* dst_w = (const float*)d_in[3];
  const float* rel_emb = (const float*)d_in[4];
  const float* rel_w = (const float*)d_in[5];
  const int* src_idx = (const int*)d_in[6];
  const int* dst_idx = (const int*)d_in[7];
  float* out = (float*)d_out;

  // workspace carve (~34 MB)
  unsigned short* fs16 = (unsigned short*)d_ws;        // 50000*256 bf16
  float* rel = (float*)(fs16 + (size_t)N_SRCN * 256);  // 512
  float* es = rel + 512;                               // 50000*8
  float* ed = es + (size_t)N_SRCN * 8;                 // 50000*8
  int* counts = (int*)(ed + (size_t)N_DSTN * 8);       // 50000
  int* offs = counts + N_DSTN;                         // 50001
  int* cursor = offs + (N_DSTN + 1);                   // 50000
  int* bsum = cursor + N_DSTN;                         // 196
  int* bbase = bsum + 256;                             // 196
  int* ssrc = bbase + 256;                             // 800000
  short* bfS = (short*)(ssrc + EDGES);                 // 65536 shorts
  short* bfD = bfS + 65536;                            // 65536 shorts

  hipMemsetAsync(counts, 0, N_DSTN * sizeof(int), stream);

  rel_k<<<1, 512, 0, stream>>>(rel_emb, rel_w, rel);
  bfrag_k<<<32, 256, 0, stream>>>(src_w, bfS);
  bfrag_k<<<32, 256, 0, stream>>>(dst_w, bfD);
  // src: project + es logits + bf16 features; dst: logits only (no fd!)
  gemm_fused_k<<<782, 256, 0, stream>>>(feat_src, bfS, rel, es, fs16, 32);
  gemm_fused_k<<<782, 256, 0, stream>>>(feat_dst, bfD, rel, ed, nullptr, 0);
  hist_k<<<(EDGES + 255) / 256, 256, 0, stream>>>(dst_idx, counts);
  scan1_k<<<196, 256, 0, stream>>>(counts, offs, bsum);
  scan2_k<<<1, 256, 0, stream>>>(bsum, bbase);
  scan3_k<<<196, 256, 0, stream>>>(offs, bbase, cursor);
  scatter_k<<<(EDGES + 255) / 256, 256, 0, stream>>>(src_idx, dst_idx, cursor, ssrc);
  aggr_k<<<(N_DSTN + 3) / 4, 256, 0, stream>>>(fs16, es, ed, offs, ssrc, out);
}